// Round 2
// 1120.757 us; speedup vs baseline: 1.6830x; 1.6830x over previous
//
#include <hip/hip_runtime.h>

// LogEig of 32768 SPD 32x32 fp32 matrices via one-sided Jacobi.
//
// v3b: odd-even transposition ordering, 2 columns per lane, DPP exchange.
// 1 block = 1 wave = 4 matrices; 16 lanes/matrix; lane `sub` owns the columns
// at positions (2*sub, 2*sub+1). Even rounds rotate a lane's own two columns
// (zero communication, rotation computed once per pair). Odd rounds pair
// (pos 2s+1, pos 2s+2) = neighbor lanes: partner column fetched with DPP
// row_shl:1 (lane i <- lane i+1) and the updated column shipped back with
// row_shr:1 (lane i <- lane i-1) -- VALU-pipe moves (2 cyc) instead of
// ds_bpermute (~7 cyc on the CU's single DS unit). Paired columns always
// swap positions after the rotation; the resulting odd-even transposition
// dance covers all 496 pairs exactly once per 32-round sweep (verified at
// N=4/N=6 by hand simulation).
//
// v3 FAILED (NaN) because the DPP directions were inverted: GCN row_shr:N
// gives lane i the value from lane i-N (canonical prefix-scan direction),
// row_shl:N from lane i+N. v3 fetched lane s-1 while shipping to s-1 under
// the belief both targeted s+1 -> non-orthogonal updates -> blowup.
//
// Rationale vs v2 (tournament+bpermute, 1886 us): that kernel was DS-unit
// bound: 992 bpermutes/wave-sweep x ~7 cyc x 640 wave-sweeps/CU = 4.4M cyc
// vs 4.85M measured; VALUBusy 49%, MfmaUtil 0, HBM 1.2%. Main loop now
// issues ZERO DS instructions; LDS only in the 4-phase epilogue (4.7 KB).

typedef float v2f __attribute__((ext_vector_type(2)));

#define SWEEPS 10

static __device__ __forceinline__ float dpp_next(float v) {
    // lane i <- lane i+1 within its 16-lane row (row_shl:1).
    // Row tail (lane 15) has no source -> bound_ctrl=false keeps own value.
    return __builtin_bit_cast(float, __builtin_amdgcn_update_dpp(
        __builtin_bit_cast(int, v), __builtin_bit_cast(int, v),
        0x101 /*row_shl:1*/, 0xF, 0xF, false));
}
static __device__ __forceinline__ float dpp_ship(float oldv, float srcv) {
    // lane i <- srcv from lane i-1 within its row (row_shr:1).
    // Row head (lane 0) has no source -> keeps oldv (position 0 idle).
    return __builtin_bit_cast(float, __builtin_amdgcn_update_dpp(
        __builtin_bit_cast(int, oldv), __builtin_bit_cast(int, srcv),
        0x111 /*row_shr:1*/, 0xF, 0xF, false));
}

static __device__ __forceinline__ void make_rot(float dot, float gpp, float gqq,
                                                float& cr, float& sr) {
    // Jacobi rotation zeroing Gram(p,q); small root t of t^2 + 2*tau*t - 1 = 0.
    const float tau = (gqq - gpp) * 0.5f * __builtin_amdgcn_rcpf(dot);
    const float at  = fabsf(tau);
    float t = __builtin_amdgcn_rcpf(at + __builtin_amdgcn_sqrtf(fmaf(at, at, 1.f)));
    t = copysignf(t, tau);
    if (fabsf(dot) < 1e-37f) t = 0.f;   // skip / kill 0/0 NaN
    cr = __builtin_amdgcn_rsqf(fmaf(t, t, 1.f));
    sr = t * cr;
}

__global__ __launch_bounds__(64, 4) void logeig_kernel(const float* __restrict__ P,
                                                       float* __restrict__ out,
                                                       int nmat) {
    const int lane = threadIdx.x;     // 0..63
    const int sub  = lane & 15;       // lane within matrix
    const int mg   = lane >> 4;       // matrix slot within wave (0..3)
    int mat = blockIdx.x * 4 + mg;
    if (mat >= nmat) mat = nmat - 1;

    // Load columns 2*sub and 2*sub+1 (P symmetric -> column == row, contiguous).
    v2f X[16], Y[16];
    {
        const float4* s4 =
            reinterpret_cast<const float4*>(P + (size_t)mat * 1024 + (size_t)sub * 64);
        #pragma unroll
        for (int k = 0; k < 8; ++k) {
            float4 v = s4[k];
            X[2*k]   = (v2f){v.x, v.y};
            X[2*k+1] = (v2f){v.z, v.w};
        }
        #pragma unroll
        for (int k = 0; k < 8; ++k) {
            float4 v = s4[8 + k];
            Y[2*k]   = (v2f){v.x, v.y};
            Y[2*k+1] = (v2f){v.z, v.w};
        }
    }

    const bool tail = (sub == 15);    // its Y = position 31: idle in odd rounds

    #pragma unroll 1
    for (int sweep = 0; sweep < SWEEPS; ++sweep) {
        #pragma unroll 1
        for (int rr = 0; rr < 16; ++rr) {
            // ---------- even round: local pair (u = X @ pos 2s, v = Y @ pos 2s+1)
            {
                v2f dA={0,0}, dB={0,0}, pA={0,0}, pB={0,0}, qA={0,0}, qB={0,0};
                #pragma unroll
                for (int k = 0; k < 16; k += 2) {
                    dA += X[k]   * Y[k];
                    pA += X[k]   * X[k];
                    qA += Y[k]   * Y[k];
                    dB += X[k+1] * Y[k+1];
                    pB += X[k+1] * X[k+1];
                    qB += Y[k+1] * Y[k+1];
                }
                v2f dT = dA + dB, pT = pA + pB, qT = qA + qB;
                float cr, sr;
                make_rot(dT[0] + dT[1], pT[0] + pT[1], qT[0] + qT[1], cr, sr);
                // always-swap: pos 2s <- v' = cr*Y + sr*X ; pos 2s+1 <- u' = cr*X - sr*Y
                #pragma unroll
                for (int k = 0; k < 16; ++k) {
                    v2f xo = X[k];
                    X[k] = cr * Y[k] + sr * xo;
                    Y[k] = cr * xo  - sr * Y[k];
                }
            }
            // ---------- odd round: pair (u = Y_s @ pos 2s+1, v = X_{s+1} @ pos 2s+2)
            {
                v2f dA={0,0}, dB={0,0}, pA={0,0}, pB={0,0}, qA={0,0}, qB={0,0};
                #pragma unroll
                for (int k = 0; k < 16; ++k) {
                    v2f o;
                    o[0] = dpp_next(X[k][0]);
                    o[1] = dpp_next(X[k][1]);
                    if (k & 1) { dB += Y[k] * o; qB += o * o; pB += Y[k] * Y[k]; }
                    else       { dA += Y[k] * o; qA += o * o; pA += Y[k] * Y[k]; }
                }
                v2f dT = dA + dB, pT = pA + pB, qT = qA + qB;
                float cr, sr;
                make_rot(dT[0] + dT[1], pT[0] + pT[1], qT[0] + qT[1], cr, sr);
                // boundary: position 31 (tail lane's Y) is unpaired -> (cr,sr)=(0,1)
                // makes Y' = Y exactly; its shipped u' dies at the row boundary.
                cr = tail ? 0.f : cr;
                sr = tail ? 1.f : sr;
                #pragma unroll
                for (int k = 0; k < 16; ++k) {
                    v2f o;                      // refetch: X untouched until recv below
                    o[0] = dpp_next(X[k][0]);
                    o[1] = dpp_next(X[k][1]);
                    v2f yo = Y[k];
                    Y[k] = cr * o  + sr * yo;   // v' stays at pos 2s+1
                    v2f u = cr * yo - sr * o;   // u' ships to pos 2s+2 (lane s+1's X)
                    X[k][0] = dpp_ship(X[k][0], u[0]);   // lane 0 keeps X (pos 0 idle)
                    X[k][1] = dpp_ship(X[k][1], u[1]);
                }
            }
        }
    }

    // ---------- epilogue: sigma, log, normalize; X = sum_c l_c u_c u_c^T ----------
    float nx2, ny2;
    {
        v2f a={0,0}, b={0,0};
        #pragma unroll
        for (int k = 0; k < 16; k += 2) { a += X[k]*X[k]; b += X[k+1]*X[k+1]; }
        v2f t = a + b; nx2 = t[0] + t[1];
    }
    {
        v2f a={0,0}, b={0,0};
        #pragma unroll
        for (int k = 0; k < 16; k += 2) { a += Y[k]*Y[k]; b += Y[k+1]*Y[k+1]; }
        v2f t = a + b; ny2 = t[0] + t[1];
    }
    const float invx = __builtin_amdgcn_rsqf(nx2);               // 1/sigma
    const float invy = __builtin_amdgcn_rsqf(ny2);
    const float lgx  = 0.34657359f * __builtin_amdgcn_logf(nx2); // ln(sigma)
    const float lgy  = 0.34657359f * __builtin_amdgcn_logf(ny2);

    // One matrix per phase; 4.7 KB total so occupancy is VGPR-limited, not LDS.
    // Row stride 36 floats keeps every 16-float half 16B-aligned; log(eig) is
    // stashed in the pad at [c][33].
    __shared__ __align__(16) float S[32][36];

    const int r = lane >> 1;       // output row this lane accumulates
    const int h = lane & 1;        // which 16-float half of that row

    #pragma unroll 1
    for (int ph = 0; ph < 4; ++ph) {
        __syncthreads();           // protect S reuse across phases
        if (mg == ph) {
            #pragma unroll
            for (int k = 0; k < 16; ++k) {
                *reinterpret_cast<v2f*>(&S[2*sub][2*k])   = X[k] * invx;
                *reinterpret_cast<v2f*>(&S[2*sub+1][2*k]) = Y[k] * invy;
            }
            S[2*sub][33]   = lgx;
            S[2*sub+1][33] = lgy;
        }
        __syncthreads();

        // All 64 lanes cooperate: lane computes half-row (r, h) of matrix ph.
        v2f acc[8];
        #pragma unroll
        for (int j = 0; j < 8; ++j) acc[j] = (v2f){0.f, 0.f};
        #pragma unroll 4
        for (int c = 0; c < 32; ++c) {
            const float m = S[c][r] * S[c][33];          // u_c[r] * log(lambda_c)
            const float4* row4 = reinterpret_cast<const float4*>(&S[c][h * 16]);
            #pragma unroll
            for (int j4 = 0; j4 < 4; ++j4) {
                float4 v = row4[j4];
                acc[2*j4]   += m * (v2f){v.x, v.y};
                acc[2*j4+1] += m * (v2f){v.z, v.w};
            }
        }
        int m2 = blockIdx.x * 4 + ph;
        if (m2 >= nmat) m2 = nmat - 1;
        // lane -> (r,h): consecutive lanes write consecutive 16B -> fully coalesced.
        float4* d4 = reinterpret_cast<float4*>(out + (size_t)m2 * 1024 +
                                               (size_t)r * 32 + h * 16);
        #pragma unroll
        for (int j4 = 0; j4 < 4; ++j4)
            d4[j4] = make_float4(acc[2*j4][0], acc[2*j4][1],
                                 acc[2*j4+1][0], acc[2*j4+1][1]);
    }
}

extern "C" void kernel_launch(void* const* d_in, const int* in_sizes, int n_in,
                              void* d_out, int out_size, void* d_ws, size_t ws_size,
                              hipStream_t stream) {
    const float* P = (const float*)d_in[0];
    float* out = (float*)d_out;
    const int nmat = in_sizes[0] / 1024;     // 32768
    const int nblocks = (nmat + 3) / 4;      // 4 matrices per 64-thread block
    logeig_kernel<<<nblocks, 64, 0, stream>>>(P, out, nmat);
}